// Round 13
// baseline (594.754 us; speedup 1.0000x reference)
//
#include <hip/hip_runtime.h>
#include <math.h>

#define EPS 1e-8f
#define TAU 1e-4f

typedef _Float16 half_t;
typedef __attribute__((ext_vector_type(8))) _Float16 f16x8;
typedef __attribute__((ext_vector_type(4))) float f32x4;

__device__ __forceinline__ void gload16(const half_t* g, half_t* l) {
    __builtin_amdgcn_global_load_lds((const __attribute__((address_space(1))) void*)g,
                                     (__attribute__((address_space(3))) void*)l, 16, 0, 0);
}

__device__ __forceinline__ void split2(float a, half_t& h, half_t& l) {
    h = (half_t)a;
    l = (half_t)(a - (float)h);
}

// ===========================================================================
// Fused prep (also zeroes the ambiguous-row counter; cnt is in its own carve,
// never clobbered by the GEMM pipeline).
// ===========================================================================
__global__ __launch_bounds__(256) void prep_kernel(
    const float* __restrict__ emb, float* __restrict__ enT,
    half_t* __restrict__ eTh, half_t* __restrict__ eTl,
    const float* __restrict__ W1, half_t* __restrict__ W1h, half_t* __restrict__ W1l,
    const float* __restrict__ W2, half_t* __restrict__ W2h, half_t* __restrict__ W2l,
    const float* __restrict__ W3, half_t* __restrict__ W3h, half_t* __restrict__ W3l,
    int* __restrict__ cnt)
{
    const int b = blockIdx.x;
    const int t = threadIdx.x;
    if (b == 0 && t == 0) *cnt = 0;
    if (b < 250) {
        const int row = b * 4 + (t >> 6);
        const int lane = t & 63;
        float e0 = emb[row * 128 + lane];
        float e1 = emb[row * 128 + 64 + lane];
        float s = e0 * e0 + e1 * e1;
#pragma unroll
        for (int off = 32; off >= 1; off >>= 1) s += __shfl_xor(s, off);
        float denom = fmaxf(sqrtf(s), EPS);
        enT[(size_t)lane * 1000 + row]        = e0 / denom;
        enT[(size_t)(64 + lane) * 1000 + row] = e1 / denom;
    } else if (b < 506) {
        const int n = (b - 250) * 4 + (t >> 6);
        const int lane = t & 63;
        float e0 = 0.f, e1 = 0.f;
        if (n < 1000) {
            e0 = emb[n * 128 + lane];
            e1 = emb[n * 128 + 64 + lane];
        }
        float s = e0 * e0 + e1 * e1;
#pragma unroll
        for (int off = 32; off >= 1; off >>= 1) s += __shfl_xor(s, off);
        float denom = fmaxf(sqrtf(s), EPS);
        float v0 = (n < 1000) ? e0 / denom : 0.f;
        float v1 = (n < 1000) ? e1 / denom : 0.f;
        half_t h, l;
        int f0 = lane, f1 = 64 + lane;
        size_t p0 = ((size_t)(f0 >> 3) * 1024 + n) * 8 + (f0 & 7);
        size_t p1 = ((size_t)(f1 >> 3) * 1024 + n) * 8 + (f1 & 7);
        split2(v0, h, l); eTh[p0] = h; eTl[p0] = l;
        split2(v1, h, l); eTh[p1] = h; eTl[p1] = l;
    } else if (b < 2554) {
        int idx = (b - 506) * 256 + t;
        int k = idx / 512, n = idx % 512;
        half_t h, l;
        split2(W1[idx], h, l);
        size_t pos = ((size_t)(k >> 3) * 512 + n) * 8 + (k & 7);
        W1h[pos] = h; W1l[pos] = l;
    } else if (b < 3066) {
        int idx = (b - 2554) * 256 + t;
        int k = idx / 256, n = idx % 256;
        half_t h, l;
        split2(W2[idx], h, l);
        size_t pos = ((size_t)(k >> 3) * 256 + n) * 8 + (k & 7);
        W2h[pos] = h; W2l[pos] = l;
    } else {
        int idx = (b - 3066) * 256 + t;
        int k = idx / 128, n = idx % 128;
        half_t h, l;
        split2(W3[idx], h, l);
        size_t pos = ((size_t)(k >> 3) * 128 + n) * 8 + (k & 7);
        W3h[pos] = h; W3l[pos] = l;
    }
}

// enT fp32 — standalone (ws-too-small fallback path only)
__global__ __launch_bounds__(64) void emb_norm_kernel(const float* __restrict__ emb,
                                                      float* __restrict__ enT) {
    const int row = blockIdx.x;
    const int t = threadIdx.x;
    float e0 = emb[row * 128 + t];
    float e1 = emb[row * 128 + 64 + t];
    float s = e0 * e0 + e1 * e1;
#pragma unroll
    for (int off = 32; off >= 1; off >>= 1) s += __shfl_xor(s, off);
    float denom = fmaxf(sqrtf(s), EPS);
    enT[(size_t)t * 1000 + row]        = e0 / denom;
    enT[(size_t)(64 + t) * 1000 + row] = e1 / denom;
}

// ===========================================================================
// MFMA GEMM — round-9 verified structure EXACTLY (best measured: 36% MfmaUtil,
// 2 blocks/CU). Tile 128x128, BK=64, A+B LDS staged, XOR swizzle, 512 thr =
// 8 waves (4 wm x 2 wn, 32x64/wave). LDS 64 KB. EPI: RELU/NORM.
// Five pipelining variants (BK=32, B-from-global, drain-0 dbuf, counted-vmcnt
// dbuf, 4-wave) all measured WORSE — this is the m97-structure ceiling.
// ===========================================================================
#define EPI_RELU 0
#define EPI_NORM 1

template<int K, int N, bool AF32, int EPI>
__global__ __launch_bounds__(512, 4) void gemm16(
    const float* __restrict__ A32,
    const half_t* __restrict__ Agh, const half_t* __restrict__ Agl,
    const half_t* __restrict__ Bgh, const half_t* __restrict__ Bgl,
    const float* __restrict__ bias,
    half_t* __restrict__ Oh, half_t* __restrict__ Ol)
{
    __shared__ alignas(16) half_t sAh[8][128][8];   // [kb][row^kb][i] 16 KB
    __shared__ alignas(16) half_t sAl[8][128][8];
    __shared__ alignas(16) half_t sBh[8][128][8];   // [kb][col][i]
    __shared__ alignas(16) half_t sBl[8][128][8];

    const int t = threadIdx.x;
    const int lane = t & 63, w = t >> 6;        // w in 0..7
    const int lr = lane & 15, lg = lane >> 4;
    const int wm = w >> 1, wn = w & 1;          // wm 0..3 (32-row), wn 0..1 (64-col)

    // ---- XCD-chunked bijective swizzle (requires nwg % 8 == 0) ----
    const int nwg = gridDim.x * gridDim.y;
    const int lin = blockIdx.x + gridDim.x * blockIdx.y;
    const int cpx = nwg >> 3;
    const int logical = (lin & 7) * cpx + (lin >> 3);
    const int bx = logical % gridDim.x;
    const int by = logical / gridDim.x;
    const int m0 = by * 128, n0 = bx * 128;

    f32x4 acc[2][4] = {};

    for (int k0 = 0; k0 < K; k0 += 64) {
        // ---- stage A (round-6 verified pattern; 1024 chunks over 512 thr) ----
        if constexpr (AF32) {
#pragma unroll
            for (int q = 0; q < 2; ++q) {
                int s = t + 512 * q;
                int row = s >> 3, kb = s & 7;
                const float* src = A32 + (size_t)(m0 + row) * K + k0 + kb * 8;
                float4 v0 = *(const float4*)src;
                float4 v1 = *(const float4*)(src + 4);
                float vv[8] = {v0.x, v0.y, v0.z, v0.w, v1.x, v1.y, v1.z, v1.w};
                f16x8 hi, lo;
#pragma unroll
                for (int i = 0; i < 8; ++i) {
                    half_t h = (half_t)vv[i];
                    hi[i] = h;
                    lo[i] = (half_t)(vv[i] - (float)h);
                }
                int prow = row ^ kb;   // XOR swizzle (2-way per 16-lane phase = free)
                *(f16x8*)&sAh[kb][prow][0] = hi;
                *(f16x8*)&sAl[kb][prow][0] = lo;
            }
        } else {
#pragma unroll
            for (int i = 0; i < 2; ++i) {
                int s = t + 512 * i;
                int kb = s >> 7, prow = s & 127;
                int row = prow ^ kb;   // pre-swizzled global source, linear LDS dest
                size_t go = (size_t)(m0 + row) * K + k0 + kb * 8;
                gload16(Agh + go, &sAh[0][0][0] + (size_t)s * 8);
                gload16(Agl + go, &sAl[0][0][0] + (size_t)s * 8);
            }
        }
        // ---- stage B (planes already in frag layout, linear) ----
#pragma unroll
        for (int i = 0; i < 2; ++i) {
            int s = t + 512 * i;
            int kb = s >> 7, col = s & 127;
            size_t go = ((size_t)(k0 / 8 + kb) * N + n0 + col) * 8;
            gload16(Bgh + go, &sBh[0][0][0] + (size_t)s * 8);
            gload16(Bgl + go, &sBl[0][0][0] + (size_t)s * 8);
        }
        __syncthreads();
        // ---- compute: 2 k-subtiles x 8 frags x 3 split passes ----
#pragma unroll
        for (int ks = 0; ks < 2; ++ks) {
            const int kb = ks * 4 + lg;
            f16x8 ah[2], al[2], bh[4], bl[4];
#pragma unroll
            for (int mf = 0; mf < 2; ++mf) {
                int row = wm * 32 + mf * 16 + lr;
                int prow = row ^ kb;
                ah[mf] = *(const f16x8*)&sAh[kb][prow][0];
                al[mf] = *(const f16x8*)&sAl[kb][prow][0];
            }
#pragma unroll
            for (int nf = 0; nf < 4; ++nf) {
                int col = wn * 64 + nf * 16 + lr;
                bh[nf] = *(const f16x8*)&sBh[kb][col][0];
                bl[nf] = *(const f16x8*)&sBl[kb][col][0];
            }
#pragma unroll
            for (int mf = 0; mf < 2; ++mf)
#pragma unroll
                for (int nf = 0; nf < 4; ++nf) {
                    acc[mf][nf] = __builtin_amdgcn_mfma_f32_16x16x32_f16(ah[mf], bh[nf], acc[mf][nf], 0, 0, 0);
                    acc[mf][nf] = __builtin_amdgcn_mfma_f32_16x16x32_f16(ah[mf], bl[nf], acc[mf][nf], 0, 0, 0);
                    acc[mf][nf] = __builtin_amdgcn_mfma_f32_16x16x32_f16(al[mf], bh[nf], acc[mf][nf], 0, 0, 0);
                }
        }
        __syncthreads();
    }

    // ---- epilogues ----
    if constexpr (EPI == EPI_RELU) {
#pragma unroll
        for (int nf = 0; nf < 4; ++nf) {
            int n = n0 + wn * 64 + nf * 16 + lr;
            float bb = bias[n];
#pragma unroll
            for (int mf = 0; mf < 2; ++mf)
#pragma unroll
                for (int r = 0; r < 4; ++r) {
                    int m = m0 + wm * 32 + mf * 16 + lg * 4 + r;
                    float v = acc[mf][nf][r] + bb;
                    v = fmaxf(v, 0.f);
                    half_t h, l;
                    split2(v, h, l);
                    Oh[(size_t)m * N + n] = h;
                    Ol[(size_t)m * N + n] = l;
                }
        }
    } else {  // EPI_NORM
        __shared__ float nsum[2][128];
#pragma unroll
        for (int nf = 0; nf < 4; ++nf) {
            float bb = bias[wn * 64 + nf * 16 + lr];
#pragma unroll
            for (int mf = 0; mf < 2; ++mf)
#pragma unroll
                for (int r = 0; r < 4; ++r) acc[mf][nf][r] += bb;
        }
#pragma unroll
        for (int mf = 0; mf < 2; ++mf)
#pragma unroll
            for (int r = 0; r < 4; ++r) {
                float s = 0.f;
#pragma unroll
                for (int nf = 0; nf < 4; ++nf) {
                    float v = acc[mf][nf][r];
                    s += v * v;
                }
#pragma unroll
                for (int off = 1; off < 16; off <<= 1) s += __shfl_xor(s, off);
                if (lr == 0) nsum[wn][wm * 32 + mf * 16 + lg * 4 + r] = s;
            }
        __syncthreads();
#pragma unroll
        for (int mf = 0; mf < 2; ++mf)
#pragma unroll
            for (int r = 0; r < 4; ++r) {
                int ml = wm * 32 + mf * 16 + lg * 4 + r;
                float tot = nsum[0][ml] + nsum[1][ml];
                float sc = 1.0f / fmaxf(sqrtf(tot), EPS);  // row-uniform: argmax-invariant
                int m = m0 + ml;
#pragma unroll
                for (int nf = 0; nf < 4; ++nf) {
                    int n = wn * 64 + nf * 16 + lr;
                    float v = acc[mf][nf][r] * sc;
                    half_t h, l;
                    split2(v, h, l);
                    Oh[(size_t)m * 128 + n] = h;
                    Ol[(size_t)m * 128 + n] = l;
                }
            }
    }
}

// ===========================================================================
// Fused sims + top2 + finalize: one block = 128 rows x all 1000 cols.
// vs round-12 sims64: rows/block doubled (64->128). pn A-fragments still in
// registers (ah/al[4][4], statically indexed); eT staged per 64-col tile.
// Doubles MFMA per barrier pair and halves eT L2 re-staging (512->256 MB).
// LDS = eT tile (32 KB) + reduce scratch.
// ===========================================================================
__global__ __launch_bounds__(256) void sims128_kernel(
    const half_t* __restrict__ pnh, const half_t* __restrict__ pnl,
    const half_t* __restrict__ eTh, const half_t* __restrict__ eTl,
    int* __restrict__ out, int* __restrict__ list, int* __restrict__ cnt,
    int Mtot)
{
    __shared__ alignas(16) half_t sEH[16 * 64 * 8];   // [kb][col][8] 16 KB
    __shared__ alignas(16) half_t sEL[16 * 64 * 8];
    __shared__ float sv1[256];    // [wn][128]
    __shared__ int   si1[256];
    __shared__ float sv2[256];

    const int t = threadIdx.x;
    const int lane = t & 63, w = t >> 6;
    const int lr = lane & 15, lg = lane >> 4;
    const int wm = w >> 1, wn = w & 1;     // wm 0..1 (64-row half), wn 0..1 (32-col half)
    const int m0 = blockIdx.x * 128;

    // ---- pn A-fragments -> registers:
    //      ah[mf][ks] = pn[(m0 + wm*64+mf*16+lr) * 128 + (ks*4+lg)*8 .. +7]
    f16x8 ah[4][4], al[4][4];
#pragma unroll
    for (int mf = 0; mf < 4; ++mf) {
        const int row = wm * 64 + mf * 16 + lr;
#pragma unroll
        for (int ks = 0; ks < 4; ++ks) {
            const int kb = ks * 4 + lg;
            size_t go = (size_t)(m0 + row) * 128 + kb * 8;
            ah[mf][ks] = *(const f16x8*)(pnh + go);
            al[mf][ks] = *(const f16x8*)(pnl + go);
        }
    }

    // ---- stage eT tile 0 ----
#pragma unroll
    for (int i = 0; i < 4; ++i) {
        int s = t + 256 * i;
        int kb = s >> 6, col = s & 63;
        size_t go = ((size_t)kb * 1024 + col) * 8;
        gload16(eTh + go, sEH + (size_t)s * 8);
        gload16(eTl + go, sEL + (size_t)s * 8);
    }

    float tv1[4][4], tv2[4][4];
    int ti1[4][4];
#pragma unroll
    for (int mf = 0; mf < 4; ++mf)
#pragma unroll
        for (int r = 0; r < 4; ++r) { tv1[mf][r] = -INFINITY; tv2[mf][r] = -INFINITY; ti1[mf][r] = 0; }

    for (int nt = 0; nt < 16; ++nt) {
        __syncthreads();   // staging (incl. global_load_lds) complete
        f32x4 acc[4][2] = {};
#pragma unroll
        for (int ks = 0; ks < 4; ++ks) {
            const int kb = ks * 4 + lg;
            f16x8 bh[2], bl[2];
#pragma unroll
            for (int nf = 0; nf < 2; ++nf) {
                int col = wn * 32 + nf * 16 + lr;
                bh[nf] = *(const f16x8*)(sEH + ((size_t)kb * 64 + col) * 8);
                bl[nf] = *(const f16x8*)(sEL + ((size_t)kb * 64 + col) * 8);
            }
#pragma unroll
            for (int mf = 0; mf < 4; ++mf)
#pragma unroll
                for (int nf = 0; nf < 2; ++nf) {
                    acc[mf][nf] = __builtin_amdgcn_mfma_f32_16x16x32_f16(ah[mf][ks], bh[nf], acc[mf][nf], 0, 0, 0);
                    acc[mf][nf] = __builtin_amdgcn_mfma_f32_16x16x32_f16(ah[mf][ks], bl[nf], acc[mf][nf], 0, 0, 0);
                    acc[mf][nf] = __builtin_amdgcn_mfma_f32_16x16x32_f16(al[mf][ks], bh[nf], acc[mf][nf], 0, 0, 0);
                }
        }
        // fold running top-2
#pragma unroll
        for (int mf = 0; mf < 4; ++mf)
#pragma unroll
            for (int nf = 0; nf < 2; ++nf) {
                int gc = nt * 64 + wn * 32 + nf * 16 + lr;
#pragma unroll
                for (int r = 0; r < 4; ++r) {
                    float v = (gc < 1000) ? acc[mf][nf][r] : -INFINITY;
                    if (v > tv1[mf][r]) { tv2[mf][r] = tv1[mf][r]; tv1[mf][r] = v; ti1[mf][r] = gc; }
                    else if (v > tv2[mf][r]) tv2[mf][r] = v;
                }
            }
        __syncthreads();   // all LDS reads done before restage
        if (nt < 15) {
            int ntn = nt + 1;
#pragma unroll
            for (int i = 0; i < 4; ++i) {
                int s = t + 256 * i;
                int kb = s >> 6, col = s & 63;
                size_t go = ((size_t)kb * 1024 + ntn * 64 + col) * 8;
                gload16(eTh + go, sEH + (size_t)s * 8);
                gload16(eTl + go, sEL + (size_t)s * 8);
            }
        }
    }

    // ---- reduce across 16 lr-lanes, then across wn halves ----
#pragma unroll
    for (int mf = 0; mf < 4; ++mf)
#pragma unroll
        for (int r = 0; r < 4; ++r) {
            float v1 = tv1[mf][r], v2 = tv2[mf][r];
            int i1 = ti1[mf][r];
#pragma unroll
            for (int off = 1; off < 16; off <<= 1) {
                float ov1 = __shfl_xor(v1, off);
                int   oi1 = __shfl_xor(i1, off);
                float ov2 = __shfl_xor(v2, off);
                if (ov1 > v1) { v2 = fmaxf(v1, ov2); v1 = ov1; i1 = oi1; }
                else if (ov1 == v1) { v2 = fmaxf(v2, ov1); if (oi1 < i1) i1 = oi1; }
                else { v2 = fmaxf(v2, ov1); }
            }
            if (lr == 0) {
                int ml = wm * 64 + mf * 16 + lg * 4 + r;   // 0..127
                sv1[wn * 128 + ml] = v1; si1[wn * 128 + ml] = i1; sv2[wn * 128 + ml] = v2;
            }
        }
    __syncthreads();
    if (t < 128) {
        float v1 = sv1[t]; int i1 = si1[t]; float v2 = sv2[t];
        float ov1 = sv1[128 + t]; int oi1 = si1[128 + t]; float ov2 = sv2[128 + t];
        if (ov1 > v1) { v2 = fmaxf(v1, ov2); v1 = ov1; i1 = oi1; }
        else if (ov1 == v1) { v2 = fmaxf(v2, ov1); if (oi1 < i1) i1 = oi1; }
        else { v2 = fmaxf(v2, ov1); }
        out[m0 + t] = i1;
        if (v1 - v2 < TAU) {
            int p = atomicAdd(cnt, 1);
            if (p < Mtot) list[p] = m0 + t;
        }
    }
}

// ===========================================================================
// Fast exact recheck: ONE BLOCK = ONE ROW, 256 threads parallel over columns.
// ===========================================================================
__global__ __launch_bounds__(256) void recheck_row_kernel(
    const float* __restrict__ img,
    const float* __restrict__ W1, const float* __restrict__ b1,
    const float* __restrict__ W2, const float* __restrict__ b2,
    const float* __restrict__ W3, const float* __restrict__ b3,
    const float* __restrict__ enT,
    const int* __restrict__ list, const int* __restrict__ count,
    int* __restrict__ out, int maxcnt)
{
    __shared__ float sx[1024];
    __shared__ float sh1[512];
    __shared__ float sh2[256];
    __shared__ float sp[128];
    __shared__ float sden;
    __shared__ float redv[4];
    __shared__ int   redi[4];

    const int t = threadIdx.x;
    const int lane = t & 63, wv = t >> 6;
    int cnt = *count;
    if (cnt > maxcnt) cnt = maxcnt;   // defensive clamp

    for (int b = blockIdx.x; b < cnt; b += gridDim.x) {
        const int row = list[b];
        *(float4*)&sx[t * 4] = *(const float4*)(img + (size_t)row * 1024 + t * 4);
        __syncthreads();
        {
            float a0 = 0.f, a1 = 0.f;
#pragma unroll 8
            for (int k = 0; k < 1024; ++k) {
                float xv = sx[k];
                float2 wv2 = *(const float2*)(W1 + (size_t)k * 512 + 2 * t);
                a0 = fmaf(xv, wv2.x, a0);
                a1 = fmaf(xv, wv2.y, a1);
            }
            sh1[2 * t]     = fmaxf(a0 + b1[2 * t], 0.f);
            sh1[2 * t + 1] = fmaxf(a1 + b1[2 * t + 1], 0.f);
        }
        __syncthreads();
        {
            float a = 0.f;
#pragma unroll 8
            for (int k = 0; k < 512; ++k)
                a = fmaf(sh1[k], W2[(size_t)k * 256 + t], a);
            sh2[t] = fmaxf(a + b2[t], 0.f);
        }
        __syncthreads();
        if (t < 128) {
            float a = 0.f;
#pragma unroll 8
            for (int k = 0; k < 256; ++k)
                a = fmaf(sh2[k], W3[(size_t)k * 128 + t], a);
            sp[t] = a + b3[t];
        }
        __syncthreads();
        if (t < 64) {
            float s = sp[t] * sp[t] + sp[t + 64] * sp[t + 64];
#pragma unroll
            for (int off = 32; off >= 1; off >>= 1) s += __shfl_xor(s, off);
            if (t == 0) sden = fmaxf(sqrtf(s), EPS);
        }
        __syncthreads();
        if (t < 128) sp[t] = sp[t] / sden;
        __syncthreads();
        float bm = -INFINITY;
        int bi = 0;
#pragma unroll
        for (int j = 0; j < 4; ++j) {
            const int c = t + 256 * j;
            if (c < 1000) {
                float a = 0.f;
#pragma unroll 8
                for (int k = 0; k < 128; ++k)
                    a = fmaf(sp[k], enT[(size_t)k * 1000 + c], a);
                if (a > bm) { bm = a; bi = c; }
            }
        }
#pragma unroll
        for (int off = 1; off < 64; off <<= 1) {
            float om = __shfl_xor(bm, off);
            int oi = __shfl_xor(bi, off);
            if (om > bm || (om == bm && oi < bi)) { bm = om; bi = oi; }
        }
        if (lane == 0) { redv[wv] = bm; redi[wv] = bi; }
        __syncthreads();
        if (t == 0) {
            float v = redv[0]; int i = redi[0];
#pragma unroll
            for (int q = 1; q < 4; ++q) {
                if (redv[q] > v || (redv[q] == v && redi[q] < i)) { v = redv[q]; i = redi[q]; }
            }
            out[row] = i;
        }
        __syncthreads();
    }
}

// ===========================================================================
// Exact fp32 path (round-1 kernel) — ws-too-small fallback only.
// ===========================================================================
__global__ __launch_bounds__(256) void scene_exact_kernel(
    const float* __restrict__ img,
    const float* __restrict__ W1, const float* __restrict__ b1,
    const float* __restrict__ W2, const float* __restrict__ b2,
    const float* __restrict__ W3, const float* __restrict__ b3,
    const float* __restrict__ enT,
    int* __restrict__ out)
{
    __shared__ float sImg[16][64];
    __shared__ float sH1[16][512];
    __shared__ float sH2[16][256];
    __shared__ float sPn[16][128];

    const int tid = threadIdx.x;
    const int base = blockIdx.x * 16;

    {
        const int tx = tid & 63, ty = tid >> 6;
        float acc[4][8] = {};
        for (int k0 = 0; k0 < 1024; k0 += 64) {
            {
                const int r = tid >> 4, c4 = tid & 15;
                float4 v = *(const float4*)(img + (size_t)(base + r) * 1024 + k0 + c4 * 4);
                *(float4*)(&sImg[r][c4 * 4]) = v;
            }
            __syncthreads();
#pragma unroll 4
            for (int kk = 0; kk < 64; ++kk) {
                const int k = k0 + kk;
                float a[4];
#pragma unroll
                for (int i = 0; i < 4; ++i) a[i] = sImg[ty + 4 * i][kk];
#pragma unroll
                for (int j = 0; j < 8; ++j) {
                    float wv = W1[(size_t)k * 512 + tx + 64 * j];
#pragma unroll
                    for (int i = 0; i < 4; ++i) acc[i][j] = fmaf(a[i], wv, acc[i][j]);
                }
            }
            __syncthreads();
        }
#pragma unroll
        for (int j = 0; j < 8; ++j) {
            float bb = b1[tx + 64 * j];
#pragma unroll
            for (int i = 0; i < 4; ++i) {
                float v = acc[i][j] + bb;
                sH1[ty + 4 * i][tx + 64 * j] = v > 0.f ? v : 0.f;
            }
        }
        __syncthreads();
    }
    {
        const int tx = tid & 63, ty = tid >> 6;
        float acc[4][4] = {};
#pragma unroll 4
        for (int k = 0; k < 512; ++k) {
            float a[4];
#pragma unroll
            for (int i = 0; i < 4; ++i) a[i] = sH1[ty + 4 * i][k];
#pragma unroll
            for (int j = 0; j < 4; ++j) {
                float wv = W2[(size_t)k * 256 + tx + 64 * j];
#pragma unroll
                for (int i = 0; i < 4; ++i) acc[i][j] = fmaf(a[i], wv, acc[i][j]);
            }
        }
        __syncthreads();
#pragma unroll
        for (int j = 0; j < 4; ++j) {
            float bb = b2[tx + 64 * j];
#pragma unroll
            for (int i = 0; i < 4; ++i) {
                float v = acc[i][j] + bb;
                sH2[ty + 4 * i][tx + 64 * j] = v > 0.f ? v : 0.f;
            }
        }
        __syncthreads();
    }
    {
        const int tx = tid & 31, ty = tid >> 5;
        float acc[2][4] = {};
#pragma unroll 4
        for (int k = 0; k < 256; ++k) {
            float a[2];
#pragma unroll
            for (int i = 0; i < 2; ++i) a[i] = sH2[ty + 8 * i][k];
#pragma unroll
            for (int j = 0; j < 4; ++j) {
                float wv = W3[(size_t)k * 128 + tx + 32 * j];
#pragma unroll
                for (int i = 0; i < 2; ++i) acc[i][j] = fmaf(a[i], wv, acc[i][j]);
            }
        }
#pragma unroll
        for (int j = 0; j < 4; ++j) {
            float bb = b3[tx + 32 * j];
#pragma unroll
            for (int i = 0; i < 2; ++i) sPn[ty + 8 * i][tx + 32 * j] = acc[i][j] + bb;
        }
        __syncthreads();
    }
    {
        const int r = tid >> 4, sub = tid & 15;
        float s = 0.f;
#pragma unroll
        for (int m = 0; m < 8; ++m) {
            float v = sPn[r][sub + 16 * m];
            s += v * v;
        }
#pragma unroll
        for (int off = 1; off < 16; off <<= 1) s += __shfl_xor(s, off);
        float denom = fmaxf(sqrtf(s), EPS);
#pragma unroll
        for (int m = 0; m < 8; ++m) sPn[r][sub + 16 * m] /= denom;
        __syncthreads();
    }
    {
        const int ct = tid & 63, rg = tid >> 6;
        float bm[4]; int bi[4];
#pragma unroll
        for (int i = 0; i < 4; ++i) { bm[i] = -INFINITY; bi[i] = 0; }
#pragma unroll
        for (int tpass = 0; tpass < 2; ++tpass) {
            const int tt = ct + 64 * tpass;
            if (tt < 125) {
                const int c0 = tt * 8;
                float acc[4][8] = {};
#pragma unroll 4
                for (int k = 0; k < 128; ++k) {
                    float p[4];
#pragma unroll
                    for (int i = 0; i < 4; ++i) p[i] = sPn[rg * 4 + i][k];
                    const float* ep = enT + (size_t)k * 1000 + c0;
                    float4 e0 = *(const float4*)(ep);
                    float4 e1 = *(const float4*)(ep + 4);
                    float e[8] = {e0.x, e0.y, e0.z, e0.w, e1.x, e1.y, e1.z, e1.w};
#pragma unroll
                    for (int j = 0; j < 8; ++j)
#pragma unroll
                        for (int i = 0; i < 4; ++i) acc[i][j] = fmaf(p[i], e[j], acc[i][j]);
                }
#pragma unroll
                for (int j = 0; j < 8; ++j) {
                    const int c = c0 + j;
#pragma unroll
                    for (int i = 0; i < 4; ++i)
                        if (acc[i][j] > bm[i]) { bm[i] = acc[i][j]; bi[i] = c; }
                }
            }
        }
#pragma unroll
        for (int off = 1; off < 64; off <<= 1) {
#pragma unroll
            for (int i = 0; i < 4; ++i) {
                float om = __shfl_xor(bm[i], off);
                int oi = __shfl_xor(bi[i], off);
                if (om > bm[i] || (om == bm[i] && oi < bi[i])) { bm[i] = om; bi[i] = oi; }
            }
        }
        if (ct == 0) {
#pragma unroll
            for (int i = 0; i < 4; ++i) out[base + rg * 4 + i] = bi[i];
        }
    }
}

// ===========================================================================
extern "C" void kernel_launch(void* const* d_in, const int* in_sizes, int n_in,
                              void* d_out, int out_size, void* d_ws, size_t ws_size,
                              hipStream_t stream) {
    const float* img = (const float*)d_in[0];
    const float* W1  = (const float*)d_in[1];
    const float* b1  = (const float*)d_in[2];
    const float* W2  = (const float*)d_in[3];
    const float* b2  = (const float*)d_in[4];
    const float* W3  = (const float*)d_in[5];
    const float* b3  = (const float*)d_in[6];
    const float* emb = (const float*)d_in[7];
    int* out = (int*)d_out;
    const int B = in_sizes[0] / 1024;   // 65536

    size_t off = 0;
    auto carve = [&](size_t bytes) {
        void* p = (char*)d_ws + off;
        off += (bytes + 255) & ~(size_t)255;
        return p;
    };
    float*  enT  = (float*)carve(128 * 1000 * 4);
    half_t* W1h  = (half_t*)carve((size_t)1024 * 512 * 2);
    half_t* W1l  = (half_t*)carve((size_t)1024 * 512 * 2);
    half_t* W2h  = (half_t*)carve((size_t)512 * 256 * 2);
    half_t* W2l  = (half_t*)carve((size_t)512 * 256 * 2);
    half_t* W3h  = (half_t*)carve((size_t)256 * 128 * 2);
    half_t* W3l  = (half_t*)carve((size_t)256 * 128 * 2);
    half_t* eTh  = (half_t*)carve((size_t)16 * 1024 * 8 * 2);
    half_t* eTl  = (half_t*)carve((size_t)16 * 1024 * 8 * 2);
    int*    list = (int*)carve((size_t)B * 4);
    int*    cnt  = (int*)carve(256);
    half_t* h1h  = (half_t*)carve((size_t)B * 512 * 2);
    half_t* h1l  = (half_t*)carve((size_t)B * 512 * 2);
    half_t* h2h  = (half_t*)carve((size_t)B * 256 * 2);
    half_t* h2l  = (half_t*)carve((size_t)B * 256 * 2);
    const size_t REQUIRE = off;

    if (ws_size < REQUIRE) {
        // fallback: exact fp32 path (round-1)
        emb_norm_kernel<<<1000, 64, 0, stream>>>(emb, (float*)d_ws);
        scene_exact_kernel<<<B / 16, 256, 0, stream>>>(
            img, W1, b1, W2, b2, W3, b3, (float*)d_ws, out);
        return;
    }

    // pn planes overlay the h1 region (h1 dead after gemm2 reads it)
    half_t* pnh  = h1h;
    half_t* pnl  = (half_t*)((char*)h1h + (size_t)B * 128 * 2);

    // ---- fused prep (single dispatch; zeroes cnt) ----
    prep_kernel<<<3194, 256, 0, stream>>>(emb, enT, eTh, eTl,
                                          W1, W1h, W1l, W2, W2h, W2l, W3, W3h, W3l,
                                          cnt);

    // ---- MFMA pipeline (round-9 verified 512-thread blocks) ----
    gemm16<1024, 512, true, EPI_RELU><<<dim3(4, B / 128), 512, 0, stream>>>(
        img, nullptr, nullptr, W1h, W1l, b1, h1h, h1l);
    gemm16<512, 256, false, EPI_RELU><<<dim3(2, B / 128), 512, 0, stream>>>(
        nullptr, h1h, h1l, W2h, W2l, b2, h2h, h2l);
    gemm16<256, 128, false, EPI_NORM><<<dim3(1, B / 128), 512, 0, stream>>>(
        nullptr, h2h, h2l, W3h, W3l, b3, pnh, pnl);

    // ---- fused sims + top2 + finalize (128 rows/block, pn-in-registers) ----
    sims128_kernel<<<B / 128, 256, 0, stream>>>(
        pnh, pnl, eTh, eTl, out, list, cnt, B);

    // ---- fast exact recheck of ambiguous rows ----
    recheck_row_kernel<<<2048, 256, 0, stream>>>(
        img, W1, b1, W2, b2, W3, b3, enT, list, cnt, out, B);
}

// Round 14
// 555.460 us; speedup vs baseline: 1.0707x; 1.0707x over previous
//
#include <hip/hip_runtime.h>
#include <math.h>

#define EPS 1e-8f
#define TAU 1e-4f

typedef _Float16 half_t;
typedef __attribute__((ext_vector_type(8))) _Float16 f16x8;
typedef __attribute__((ext_vector_type(4))) float f32x4;

__device__ __forceinline__ void gload16(const half_t* g, half_t* l) {
    __builtin_amdgcn_global_load_lds((const __attribute__((address_space(1))) void*)g,
                                     (__attribute__((address_space(3))) void*)l, 16, 0, 0);
}

__device__ __forceinline__ void split2(float a, half_t& h, half_t& l) {
    h = (half_t)a;
    l = (half_t)(a - (float)h);
}

// ===========================================================================
// Fused prep (also zeroes the ambiguous-row counter; cnt is in its own carve,
// never clobbered by the GEMM pipeline).
// ===========================================================================
__global__ __launch_bounds__(256) void prep_kernel(
    const float* __restrict__ emb, float* __restrict__ enT,
    half_t* __restrict__ eTh, half_t* __restrict__ eTl,
    const float* __restrict__ W1, half_t* __restrict__ W1h, half_t* __restrict__ W1l,
    const float* __restrict__ W2, half_t* __restrict__ W2h, half_t* __restrict__ W2l,
    const float* __restrict__ W3, half_t* __restrict__ W3h, half_t* __restrict__ W3l,
    int* __restrict__ cnt)
{
    const int b = blockIdx.x;
    const int t = threadIdx.x;
    if (b == 0 && t == 0) *cnt = 0;
    if (b < 250) {
        const int row = b * 4 + (t >> 6);
        const int lane = t & 63;
        float e0 = emb[row * 128 + lane];
        float e1 = emb[row * 128 + 64 + lane];
        float s = e0 * e0 + e1 * e1;
#pragma unroll
        for (int off = 32; off >= 1; off >>= 1) s += __shfl_xor(s, off);
        float denom = fmaxf(sqrtf(s), EPS);
        enT[(size_t)lane * 1000 + row]        = e0 / denom;
        enT[(size_t)(64 + lane) * 1000 + row] = e1 / denom;
    } else if (b < 506) {
        const int n = (b - 250) * 4 + (t >> 6);
        const int lane = t & 63;
        float e0 = 0.f, e1 = 0.f;
        if (n < 1000) {
            e0 = emb[n * 128 + lane];
            e1 = emb[n * 128 + 64 + lane];
        }
        float s = e0 * e0 + e1 * e1;
#pragma unroll
        for (int off = 32; off >= 1; off >>= 1) s += __shfl_xor(s, off);
        float denom = fmaxf(sqrtf(s), EPS);
        float v0 = (n < 1000) ? e0 / denom : 0.f;
        float v1 = (n < 1000) ? e1 / denom : 0.f;
        half_t h, l;
        int f0 = lane, f1 = 64 + lane;
        size_t p0 = ((size_t)(f0 >> 3) * 1024 + n) * 8 + (f0 & 7);
        size_t p1 = ((size_t)(f1 >> 3) * 1024 + n) * 8 + (f1 & 7);
        split2(v0, h, l); eTh[p0] = h; eTl[p0] = l;
        split2(v1, h, l); eTh[p1] = h; eTl[p1] = l;
    } else if (b < 2554) {
        int idx = (b - 506) * 256 + t;
        int k = idx / 512, n = idx % 512;
        half_t h, l;
        split2(W1[idx], h, l);
        size_t pos = ((size_t)(k >> 3) * 512 + n) * 8 + (k & 7);
        W1h[pos] = h; W1l[pos] = l;
    } else if (b < 3066) {
        int idx = (b - 2554) * 256 + t;
        int k = idx / 256, n = idx % 256;
        half_t h, l;
        split2(W2[idx], h, l);
        size_t pos = ((size_t)(k >> 3) * 256 + n) * 8 + (k & 7);
        W2h[pos] = h; W2l[pos] = l;
    } else {
        int idx = (b - 3066) * 256 + t;
        int k = idx / 128, n = idx % 128;
        half_t h, l;
        split2(W3[idx], h, l);
        size_t pos = ((size_t)(k >> 3) * 128 + n) * 8 + (k & 7);
        W3h[pos] = h; W3l[pos] = l;
    }
}

// enT fp32 — standalone (ws-too-small fallback path only)
__global__ __launch_bounds__(64) void emb_norm_kernel(const float* __restrict__ emb,
                                                      float* __restrict__ enT) {
    const int row = blockIdx.x;
    const int t = threadIdx.x;
    float e0 = emb[row * 128 + t];
    float e1 = emb[row * 128 + 64 + t];
    float s = e0 * e0 + e1 * e1;
#pragma unroll
    for (int off = 32; off >= 1; off >>= 1) s += __shfl_xor(s, off);
    float denom = fmaxf(sqrtf(s), EPS);
    enT[(size_t)t * 1000 + row]        = e0 / denom;
    enT[(size_t)(64 + t) * 1000 + row] = e1 / denom;
}

// ===========================================================================
// MFMA GEMM — round-9 verified structure EXACTLY (best measured: 36% MfmaUtil,
// 2 blocks/CU). Tile 128x128, BK=64, A+B LDS staged, XOR swizzle, 512 thr =
// 8 waves (4 wm x 2 wn, 32x64/wave). LDS 64 KB. EPI: RELU/NORM.
// Five pipelining variants (BK=32, B-from-global, drain-0 dbuf, counted-vmcnt
// dbuf, 4-wave) all measured WORSE — this is the m97-structure ceiling.
// ===========================================================================
#define EPI_RELU 0
#define EPI_NORM 1

template<int K, int N, bool AF32, int EPI>
__global__ __launch_bounds__(512, 4) void gemm16(
    const float* __restrict__ A32,
    const half_t* __restrict__ Agh, const half_t* __restrict__ Agl,
    const half_t* __restrict__ Bgh, const half_t* __restrict__ Bgl,
    const float* __restrict__ bias,
    half_t* __restrict__ Oh, half_t* __restrict__ Ol)
{
    __shared__ alignas(16) half_t sAh[8][128][8];   // [kb][row^kb][i] 16 KB
    __shared__ alignas(16) half_t sAl[8][128][8];
    __shared__ alignas(16) half_t sBh[8][128][8];   // [kb][col][i]
    __shared__ alignas(16) half_t sBl[8][128][8];

    const int t = threadIdx.x;
    const int lane = t & 63, w = t >> 6;        // w in 0..7
    const int lr = lane & 15, lg = lane >> 4;
    const int wm = w >> 1, wn = w & 1;          // wm 0..3 (32-row), wn 0..1 (64-col)

    // ---- XCD-chunked bijective swizzle (requires nwg % 8 == 0) ----
    const int nwg = gridDim.x * gridDim.y;
    const int lin = blockIdx.x + gridDim.x * blockIdx.y;
    const int cpx = nwg >> 3;
    const int logical = (lin & 7) * cpx + (lin >> 3);
    const int bx = logical % gridDim.x;
    const int by = logical / gridDim.x;
    const int m0 = by * 128, n0 = bx * 128;

    f32x4 acc[2][4] = {};

    for (int k0 = 0; k0 < K; k0 += 64) {
        // ---- stage A (round-6 verified pattern; 1024 chunks over 512 thr) ----
        if constexpr (AF32) {
#pragma unroll
            for (int q = 0; q < 2; ++q) {
                int s = t + 512 * q;
                int row = s >> 3, kb = s & 7;
                const float* src = A32 + (size_t)(m0 + row) * K + k0 + kb * 8;
                float4 v0 = *(const float4*)src;
                float4 v1 = *(const float4*)(src + 4);
                float vv[8] = {v0.x, v0.y, v0.z, v0.w, v1.x, v1.y, v1.z, v1.w};
                f16x8 hi, lo;
#pragma unroll
                for (int i = 0; i < 8; ++i) {
                    half_t h = (half_t)vv[i];
                    hi[i] = h;
                    lo[i] = (half_t)(vv[i] - (float)h);
                }
                int prow = row ^ kb;   // XOR swizzle (2-way per 16-lane phase = free)
                *(f16x8*)&sAh[kb][prow][0] = hi;
                *(f16x8*)&sAl[kb][prow][0] = lo;
            }
        } else {
#pragma unroll
            for (int i = 0; i < 2; ++i) {
                int s = t + 512 * i;
                int kb = s >> 7, prow = s & 127;
                int row = prow ^ kb;   // pre-swizzled global source, linear LDS dest
                size_t go = (size_t)(m0 + row) * K + k0 + kb * 8;
                gload16(Agh + go, &sAh[0][0][0] + (size_t)s * 8);
                gload16(Agl + go, &sAl[0][0][0] + (size_t)s * 8);
            }
        }
        // ---- stage B (planes already in frag layout, linear) ----
#pragma unroll
        for (int i = 0; i < 2; ++i) {
            int s = t + 512 * i;
            int kb = s >> 7, col = s & 127;
            size_t go = ((size_t)(k0 / 8 + kb) * N + n0 + col) * 8;
            gload16(Bgh + go, &sBh[0][0][0] + (size_t)s * 8);
            gload16(Bgl + go, &sBl[0][0][0] + (size_t)s * 8);
        }
        __syncthreads();
        // ---- compute: 2 k-subtiles x 8 frags x 3 split passes ----
#pragma unroll
        for (int ks = 0; ks < 2; ++ks) {
            const int kb = ks * 4 + lg;
            f16x8 ah[2], al[2], bh[4], bl[4];
#pragma unroll
            for (int mf = 0; mf < 2; ++mf) {
                int row = wm * 32 + mf * 16 + lr;
                int prow = row ^ kb;
                ah[mf] = *(const f16x8*)&sAh[kb][prow][0];
                al[mf] = *(const f16x8*)&sAl[kb][prow][0];
            }
#pragma unroll
            for (int nf = 0; nf < 4; ++nf) {
                int col = wn * 64 + nf * 16 + lr;
                bh[nf] = *(const f16x8*)&sBh[kb][col][0];
                bl[nf] = *(const f16x8*)&sBl[kb][col][0];
            }
#pragma unroll
            for (int mf = 0; mf < 2; ++mf)
#pragma unroll
                for (int nf = 0; nf < 4; ++nf) {
                    acc[mf][nf] = __builtin_amdgcn_mfma_f32_16x16x32_f16(ah[mf], bh[nf], acc[mf][nf], 0, 0, 0);
                    acc[mf][nf] = __builtin_amdgcn_mfma_f32_16x16x32_f16(ah[mf], bl[nf], acc[mf][nf], 0, 0, 0);
                    acc[mf][nf] = __builtin_amdgcn_mfma_f32_16x16x32_f16(al[mf], bh[nf], acc[mf][nf], 0, 0, 0);
                }
        }
        __syncthreads();
    }

    // ---- epilogues ----
    if constexpr (EPI == EPI_RELU) {
#pragma unroll
        for (int nf = 0; nf < 4; ++nf) {
            int n = n0 + wn * 64 + nf * 16 + lr;
            float bb = bias[n];
#pragma unroll
            for (int mf = 0; mf < 2; ++mf)
#pragma unroll
                for (int r = 0; r < 4; ++r) {
                    int m = m0 + wm * 32 + mf * 16 + lg * 4 + r;
                    float v = acc[mf][nf][r] + bb;
                    v = fmaxf(v, 0.f);
                    half_t h, l;
                    split2(v, h, l);
                    Oh[(size_t)m * N + n] = h;
                    Ol[(size_t)m * N + n] = l;
                }
        }
    } else {  // EPI_NORM
        __shared__ float nsum[2][128];
#pragma unroll
        for (int nf = 0; nf < 4; ++nf) {
            float bb = bias[wn * 64 + nf * 16 + lr];
#pragma unroll
            for (int mf = 0; mf < 2; ++mf)
#pragma unroll
                for (int r = 0; r < 4; ++r) acc[mf][nf][r] += bb;
        }
#pragma unroll
        for (int mf = 0; mf < 2; ++mf)
#pragma unroll
            for (int r = 0; r < 4; ++r) {
                float s = 0.f;
#pragma unroll
                for (int nf = 0; nf < 4; ++nf) {
                    float v = acc[mf][nf][r];
                    s += v * v;
                }
#pragma unroll
                for (int off = 1; off < 16; off <<= 1) s += __shfl_xor(s, off);
                if (lr == 0) nsum[wn][wm * 32 + mf * 16 + lg * 4 + r] = s;
            }
        __syncthreads();
#pragma unroll
        for (int mf = 0; mf < 2; ++mf)
#pragma unroll
            for (int r = 0; r < 4; ++r) {
                int ml = wm * 32 + mf * 16 + lg * 4 + r;
                float tot = nsum[0][ml] + nsum[1][ml];
                float sc = 1.0f / fmaxf(sqrtf(tot), EPS);  // row-uniform: argmax-invariant
                int m = m0 + ml;
#pragma unroll
                for (int nf = 0; nf < 4; ++nf) {
                    int n = wn * 64 + nf * 16 + lr;
                    float v = acc[mf][nf][r] * sc;
                    half_t h, l;
                    split2(v, h, l);
                    Oh[(size_t)m * 128 + n] = h;
                    Ol[(size_t)m * 128 + n] = l;
                }
            }
    }
}

// ===========================================================================
// Fused sims + top2 + finalize: one block = 64 rows x all 1000 cols.
// pn A-fragments held IN REGISTERS (each lane only uses kb = ks*4+lg,
// ks 0..3 -> 16 f16x8/plane-pair), loaded once from the pn planes. No pn LDS;
// LDS = eT tile only (32 KB). Verified round 12 (best tail config; the
// 128-row variant measured worse — VGPR pressure).
// ===========================================================================
__global__ __launch_bounds__(256, 2) void sims64_kernel(
    const half_t* __restrict__ pnh, const half_t* __restrict__ pnl,
    const half_t* __restrict__ eTh, const half_t* __restrict__ eTl,
    int* __restrict__ out, int* __restrict__ list, int* __restrict__ cnt,
    int Mtot)
{
    __shared__ alignas(16) half_t sEH[16 * 64 * 8];   // [kb][col][8] 16 KB
    __shared__ alignas(16) half_t sEL[16 * 64 * 8];
    __shared__ float sv1[128];
    __shared__ int   si1[128];
    __shared__ float sv2[128];

    const int t = threadIdx.x;
    const int lane = t & 63, w = t >> 6;
    const int lr = lane & 15, lg = lane >> 4;
    const int wm = w >> 1, wn = w & 1;
    const int m0 = blockIdx.x * 64;

    // ---- pn A-fragments -> registers ----
    f16x8 ah[2][4], al[2][4];
#pragma unroll
    for (int mf = 0; mf < 2; ++mf) {
        const int row = wm * 32 + mf * 16 + lr;
#pragma unroll
        for (int ks = 0; ks < 4; ++ks) {
            const int kb = ks * 4 + lg;
            size_t go = (size_t)(m0 + row) * 128 + kb * 8;
            ah[mf][ks] = *(const f16x8*)(pnh + go);
            al[mf][ks] = *(const f16x8*)(pnl + go);
        }
    }

    // ---- stage eT tile 0 ----
#pragma unroll
    for (int i = 0; i < 4; ++i) {
        int s = t + 256 * i;
        int kb = s >> 6, col = s & 63;
        size_t go = ((size_t)kb * 1024 + col) * 8;
        gload16(eTh + go, sEH + (size_t)s * 8);
        gload16(eTl + go, sEL + (size_t)s * 8);
    }

    float tv1[2][4], tv2[2][4];
    int ti1[2][4];
#pragma unroll
    for (int mf = 0; mf < 2; ++mf)
#pragma unroll
        for (int r = 0; r < 4; ++r) { tv1[mf][r] = -INFINITY; tv2[mf][r] = -INFINITY; ti1[mf][r] = 0; }

    for (int nt = 0; nt < 16; ++nt) {
        __syncthreads();   // staging (incl. global_load_lds) complete
        f32x4 acc[2][2] = {};
#pragma unroll
        for (int ks = 0; ks < 4; ++ks) {
            const int kb = ks * 4 + lg;
            f16x8 bh[2], bl[2];
#pragma unroll
            for (int nf = 0; nf < 2; ++nf) {
                int col = wn * 32 + nf * 16 + lr;
                bh[nf] = *(const f16x8*)(sEH + ((size_t)kb * 64 + col) * 8);
                bl[nf] = *(const f16x8*)(sEL + ((size_t)kb * 64 + col) * 8);
            }
#pragma unroll
            for (int mf = 0; mf < 2; ++mf)
#pragma unroll
                for (int nf = 0; nf < 2; ++nf) {
                    acc[mf][nf] = __builtin_amdgcn_mfma_f32_16x16x32_f16(ah[mf][ks], bh[nf], acc[mf][nf], 0, 0, 0);
                    acc[mf][nf] = __builtin_amdgcn_mfma_f32_16x16x32_f16(ah[mf][ks], bl[nf], acc[mf][nf], 0, 0, 0);
                    acc[mf][nf] = __builtin_amdgcn_mfma_f32_16x16x32_f16(al[mf][ks], bh[nf], acc[mf][nf], 0, 0, 0);
                }
        }
        // fold running top-2
#pragma unroll
        for (int mf = 0; mf < 2; ++mf)
#pragma unroll
            for (int nf = 0; nf < 2; ++nf) {
                int gc = nt * 64 + wn * 32 + nf * 16 + lr;
#pragma unroll
                for (int r = 0; r < 4; ++r) {
                    float v = (gc < 1000) ? acc[mf][nf][r] : -INFINITY;
                    if (v > tv1[mf][r]) { tv2[mf][r] = tv1[mf][r]; tv1[mf][r] = v; ti1[mf][r] = gc; }
                    else if (v > tv2[mf][r]) tv2[mf][r] = v;
                }
            }
        __syncthreads();   // all LDS reads done before restage
        if (nt < 15) {
            int ntn = nt + 1;
#pragma unroll
            for (int i = 0; i < 4; ++i) {
                int s = t + 256 * i;
                int kb = s >> 6, col = s & 63;
                size_t go = ((size_t)kb * 1024 + ntn * 64 + col) * 8;
                gload16(eTh + go, sEH + (size_t)s * 8);
                gload16(eTl + go, sEL + (size_t)s * 8);
            }
        }
    }

    // ---- reduce across 16 lr-lanes, then across wn halves ----
#pragma unroll
    for (int mf = 0; mf < 2; ++mf)
#pragma unroll
        for (int r = 0; r < 4; ++r) {
            float v1 = tv1[mf][r], v2 = tv2[mf][r];
            int i1 = ti1[mf][r];
#pragma unroll
            for (int off = 1; off < 16; off <<= 1) {
                float ov1 = __shfl_xor(v1, off);
                int   oi1 = __shfl_xor(i1, off);
                float ov2 = __shfl_xor(v2, off);
                if (ov1 > v1) { v2 = fmaxf(v1, ov2); v1 = ov1; i1 = oi1; }
                else if (ov1 == v1) { v2 = fmaxf(v2, ov1); if (oi1 < i1) i1 = oi1; }
                else { v2 = fmaxf(v2, ov1); }
            }
            if (lr == 0) {
                int ml = wm * 32 + mf * 16 + lg * 4 + r;   // 0..63
                sv1[wn * 64 + ml] = v1; si1[wn * 64 + ml] = i1; sv2[wn * 64 + ml] = v2;
            }
        }
    __syncthreads();
    if (t < 64) {
        float v1 = sv1[t]; int i1 = si1[t]; float v2 = sv2[t];
        float ov1 = sv1[64 + t]; int oi1 = si1[64 + t]; float ov2 = sv2[64 + t];
        if (ov1 > v1) { v2 = fmaxf(v1, ov2); v1 = ov1; i1 = oi1; }
        else if (ov1 == v1) { v2 = fmaxf(v2, ov1); if (oi1 < i1) i1 = oi1; }
        else { v2 = fmaxf(v2, ov1); }
        out[m0 + t] = i1;
        if (v1 - v2 < TAU) {
            int p = atomicAdd(cnt, 1);
            if (p < Mtot) list[p] = m0 + t;
        }
    }
}

// ===========================================================================
// Fast exact recheck: ONE BLOCK = ONE ROW, 256 threads parallel over columns.
// ===========================================================================
__global__ __launch_bounds__(256) void recheck_row_kernel(
    const float* __restrict__ img,
    const float* __restrict__ W1, const float* __restrict__ b1,
    const float* __restrict__ W2, const float* __restrict__ b2,
    const float* __restrict__ W3, const float* __restrict__ b3,
    const float* __restrict__ enT,
    const int* __restrict__ list, const int* __restrict__ count,
    int* __restrict__ out, int maxcnt)
{
    __shared__ float sx[1024];
    __shared__ float sh1[512];
    __shared__ float sh2[256];
    __shared__ float sp[128];
    __shared__ float sden;
    __shared__ float redv[4];
    __shared__ int   redi[4];

    const int t = threadIdx.x;
    const int lane = t & 63, wv = t >> 6;
    int cnt = *count;
    if (cnt > maxcnt) cnt = maxcnt;   // defensive clamp

    for (int b = blockIdx.x; b < cnt; b += gridDim.x) {
        const int row = list[b];
        *(float4*)&sx[t * 4] = *(const float4*)(img + (size_t)row * 1024 + t * 4);
        __syncthreads();
        {
            float a0 = 0.f, a1 = 0.f;
#pragma unroll 8
            for (int k = 0; k < 1024; ++k) {
                float xv = sx[k];
                float2 wv2 = *(const float2*)(W1 + (size_t)k * 512 + 2 * t);
                a0 = fmaf(xv, wv2.x, a0);
                a1 = fmaf(xv, wv2.y, a1);
            }
            sh1[2 * t]     = fmaxf(a0 + b1[2 * t], 0.f);
            sh1[2 * t + 1] = fmaxf(a1 + b1[2 * t + 1], 0.f);
        }
        __syncthreads();
        {
            float a = 0.f;
#pragma unroll 8
            for (int k = 0; k < 512; ++k)
                a = fmaf(sh1[k], W2[(size_t)k * 256 + t], a);
            sh2[t] = fmaxf(a + b2[t], 0.f);
        }
        __syncthreads();
        if (t < 128) {
            float a = 0.f;
#pragma unroll 8
            for (int k = 0; k < 256; ++k)
                a = fmaf(sh2[k], W3[(size_t)k * 128 + t], a);
            sp[t] = a + b3[t];
        }
        __syncthreads();
        if (t < 64) {
            float s = sp[t] * sp[t] + sp[t + 64] * sp[t + 64];
#pragma unroll
            for (int off = 32; off >= 1; off >>= 1) s += __shfl_xor(s, off);
            if (t == 0) sden = fmaxf(sqrtf(s), EPS);
        }
        __syncthreads();
        if (t < 128) sp[t] = sp[t] / sden;
        __syncthreads();
        float bm = -INFINITY;
        int bi = 0;
#pragma unroll
        for (int j = 0; j < 4; ++j) {
            const int c = t + 256 * j;
            if (c < 1000) {
                float a = 0.f;
#pragma unroll 8
                for (int k = 0; k < 128; ++k)
                    a = fmaf(sp[k], enT[(size_t)k * 1000 + c], a);
                if (a > bm) { bm = a; bi = c; }
            }
        }
#pragma unroll
        for (int off = 1; off < 64; off <<= 1) {
            float om = __shfl_xor(bm, off);
            int oi = __shfl_xor(bi, off);
            if (om > bm || (om == bm && oi < bi)) { bm = om; bi = oi; }
        }
        if (lane == 0) { redv[wv] = bm; redi[wv] = bi; }
        __syncthreads();
        if (t == 0) {
            float v = redv[0]; int i = redi[0];
#pragma unroll
            for (int q = 1; q < 4; ++q) {
                if (redv[q] > v || (redv[q] == v && redi[q] < i)) { v = redv[q]; i = redi[q]; }
            }
            out[row] = i;
        }
        __syncthreads();
    }
}

// ===========================================================================
// Exact fp32 path (round-1 kernel) — ws-too-small fallback only.
// ===========================================================================
__global__ __launch_bounds__(256) void scene_exact_kernel(
    const float* __restrict__ img,
    const float* __restrict__ W1, const float* __restrict__ b1,
    const float* __restrict__ W2, const float* __restrict__ b2,
    const float* __restrict__ W3, const float* __restrict__ b3,
    const float* __restrict__ enT,
    int* __restrict__ out)
{
    __shared__ float sImg[16][64];
    __shared__ float sH1[16][512];
    __shared__ float sH2[16][256];
    __shared__ float sPn[16][128];

    const int tid = threadIdx.x;
    const int base = blockIdx.x * 16;

    {
        const int tx = tid & 63, ty = tid >> 6;
        float acc[4][8] = {};
        for (int k0 = 0; k0 < 1024; k0 += 64) {
            {
                const int r = tid >> 4, c4 = tid & 15;
                float4 v = *(const float4*)(img + (size_t)(base + r) * 1024 + k0 + c4 * 4);
                *(float4*)(&sImg[r][c4 * 4]) = v;
            }
            __syncthreads();
#pragma unroll 4
            for (int kk = 0; kk < 64; ++kk) {
                const int k = k0 + kk;
                float a[4];
#pragma unroll
                for (int i = 0; i < 4; ++i) a[i] = sImg[ty + 4 * i][kk];
#pragma unroll
                for (int j = 0; j < 8; ++j) {
                    float wv = W1[(size_t)k * 512 + tx + 64 * j];
#pragma unroll
                    for (int i = 0; i < 4; ++i) acc[i][j] = fmaf(a[i], wv, acc[i][j]);
                }
            }
            __syncthreads();
        }
#pragma unroll
        for (int j = 0; j < 8; ++j) {
            float bb = b1[tx + 64 * j];
#pragma unroll
            for (int i = 0; i < 4; ++i) {
                float v = acc[i][j] + bb;
                sH1[ty + 4 * i][tx + 64 * j] = v > 0.f ? v : 0.f;
            }
        }
        __syncthreads();
    }
    {
        const int tx = tid & 63, ty = tid >> 6;
        float acc[4][4] = {};
#pragma unroll 4
        for (int k = 0; k < 512; ++k) {
            float a[4];
#pragma unroll
            for (int i = 0; i < 4; ++i) a[i] = sH1[ty + 4 * i][k];
#pragma unroll
            for (int j = 0; j < 4; ++j) {
                float wv = W2[(size_t)k * 256 + tx + 64 * j];
#pragma unroll
                for (int i = 0; i < 4; ++i) acc[i][j] = fmaf(a[i], wv, acc[i][j]);
            }
        }
        __syncthreads();
#pragma unroll
        for (int j = 0; j < 4; ++j) {
            float bb = b2[tx + 64 * j];
#pragma unroll
            for (int i = 0; i < 4; ++i) {
                float v = acc[i][j] + bb;
                sH2[ty + 4 * i][tx + 64 * j] = v > 0.f ? v : 0.f;
            }
        }
        __syncthreads();
    }
    {
        const int tx = tid & 31, ty = tid >> 5;
        float acc[2][4] = {};
#pragma unroll 4
        for (int k = 0; k < 256; ++k) {
            float a[2];
#pragma unroll
            for (int i = 0; i < 2; ++i) a[i] = sH2[ty + 8 * i][k];
#pragma unroll
            for (int j = 0; j < 4; ++j) {
                float wv = W3[(size_t)k * 128 + tx + 32 * j];
#pragma unroll
                for (int i = 0; i < 2; ++i) acc[i][j] = fmaf(a[i], wv, acc[i][j]);
            }
        }
#pragma unroll
        for (int j = 0; j < 4; ++j) {
            float bb = b3[tx + 32 * j];
#pragma unroll
            for (int i = 0; i < 2; ++i) sPn[ty + 8 * i][tx + 32 * j] = acc[i][j] + bb;
        }
        __syncthreads();
    }
    {
        const int r = tid >> 4, sub = tid & 15;
        float s = 0.f;
#pragma unroll
        for (int m = 0; m < 8; ++m) {
            float v = sPn[r][sub + 16 * m];
            s += v * v;
        }
#pragma unroll
        for (int off = 1; off < 16; off <<= 1) s += __shfl_xor(s, off);
        float denom = fmaxf(sqrtf(s), EPS);
#pragma unroll
        for (int m = 0; m < 8; ++m) sPn[r][sub + 16 * m] /= denom;
        __syncthreads();
    }
    {
        const int ct = tid & 63, rg = tid >> 6;
        float bm[4]; int bi[4];
#pragma unroll
        for (int i = 0; i < 4; ++i) { bm[i] = -INFINITY; bi[i] = 0; }
#pragma unroll
        for (int tpass = 0; tpass < 2; ++tpass) {
            const int tt = ct + 64 * tpass;
            if (tt < 125) {
                const int c0 = tt * 8;
                float acc[4][8] = {};
#pragma unroll 4
                for (int k = 0; k < 128; ++k) {
                    float p[4];
#pragma unroll
                    for (int i = 0; i < 4; ++i) p[i] = sPn[rg * 4 + i][k];
                    const float* ep = enT + (size_t)k * 1000 + c0;
                    float4 e0 = *(const float4*)(ep);
                    float4 e1 = *(const float4*)(ep + 4);
                    float e[8] = {e0.x, e0.y, e0.z, e0.w, e1.x, e1.y, e1.z, e1.w};
#pragma unroll
                    for (int j = 0; j < 8; ++j)
#pragma unroll
                        for (int i = 0; i < 4; ++i) acc[i][j] = fmaf(p[i], e[j], acc[i][j]);
                }
#pragma unroll
                for (int j = 0; j < 8; ++j) {
                    const int c = c0 + j;
#pragma unroll
                    for (int i = 0; i < 4; ++i)
                        if (acc[i][j] > bm[i]) { bm[i] = acc[i][j]; bi[i] = c; }
                }
            }
        }
#pragma unroll
        for (int off = 1; off < 64; off <<= 1) {
#pragma unroll
            for (int i = 0; i < 4; ++i) {
                float om = __shfl_xor(bm[i], off);
                int oi = __shfl_xor(bi[i], off);
                if (om > bm[i] || (om == bm[i] && oi < bi[i])) { bm[i] = om; bi[i] = oi; }
            }
        }
        if (ct == 0) {
#pragma unroll
            for (int i = 0; i < 4; ++i) out[base + rg * 4 + i] = bi[i];
        }
    }
}

// ===========================================================================
extern "C" void kernel_launch(void* const* d_in, const int* in_sizes, int n_in,
                              void* d_out, int out_size, void* d_ws, size_t ws_size,
                              hipStream_t stream) {
    const float* img = (const float*)d_in[0];
    const float* W1  = (const float*)d_in[1];
    const float* b1  = (const float*)d_in[2];
    const float* W2  = (const float*)d_in[3];
    const float* b2  = (const float*)d_in[4];
    const float* W3  = (const float*)d_in[5];
    const float* b3  = (const float*)d_in[6];
    const float* emb = (const float*)d_in[7];
    int* out = (int*)d_out;
    const int B = in_sizes[0] / 1024;   // 65536

    size_t off = 0;
    auto carve = [&](size_t bytes) {
        void* p = (char*)d_ws + off;
        off += (bytes + 255) & ~(size_t)255;
        return p;
    };
    float*  enT  = (float*)carve(128 * 1000 * 4);
    half_t* W1h  = (half_t*)carve((size_t)1024 * 512 * 2);
    half_t* W1l  = (half_t*)carve((size_t)1024 * 512 * 2);
    half_t* W2h  = (half_t*)carve((size_t)512 * 256 * 2);
    half_t* W2l  = (half_t*)carve((size_t)512 * 256 * 2);
    half_t* W3h  = (half_t*)carve((size_t)256 * 128 * 2);
    half_t* W3l  = (half_t*)carve((size_t)256 * 128 * 2);
    half_t* eTh  = (half_t*)carve((size_t)16 * 1024 * 8 * 2);
    half_t* eTl  = (half_t*)carve((size_t)16 * 1024 * 8 * 2);
    int*    list = (int*)carve((size_t)B * 4);
    int*    cnt  = (int*)carve(256);
    half_t* h1h  = (half_t*)carve((size_t)B * 512 * 2);
    half_t* h1l  = (half_t*)carve((size_t)B * 512 * 2);
    half_t* h2h  = (half_t*)carve((size_t)B * 256 * 2);
    half_t* h2l  = (half_t*)carve((size_t)B * 256 * 2);
    const size_t REQUIRE = off;

    if (ws_size < REQUIRE) {
        // fallback: exact fp32 path (round-1)
        emb_norm_kernel<<<1000, 64, 0, stream>>>(emb, (float*)d_ws);
        scene_exact_kernel<<<B / 16, 256, 0, stream>>>(
            img, W1, b1, W2, b2, W3, b3, (float*)d_ws, out);
        return;
    }

    // pn planes overlay the h1 region (h1 dead after gemm2 reads it)
    half_t* pnh  = h1h;
    half_t* pnl  = (half_t*)((char*)h1h + (size_t)B * 128 * 2);

    // ---- fused prep (single dispatch; zeroes cnt) ----
    prep_kernel<<<3194, 256, 0, stream>>>(emb, enT, eTh, eTl,
                                          W1, W1h, W1l, W2, W2h, W2l, W3, W3h, W3l,
                                          cnt);

    // ---- MFMA pipeline (round-9 verified 512-thread blocks) ----
    gemm16<1024, 512, true, EPI_RELU><<<dim3(4, B / 128), 512, 0, stream>>>(
        img, nullptr, nullptr, W1h, W1l, b1, h1h, h1l);
    gemm16<512, 256, false, EPI_RELU><<<dim3(2, B / 128), 512, 0, stream>>>(
        nullptr, h1h, h1l, W2h, W2l, b2, h2h, h2l);
    gemm16<256, 128, false, EPI_NORM><<<dim3(1, B / 128), 512, 0, stream>>>(
        nullptr, h2h, h2l, W3h, W3l, b3, pnh, pnl);

    // ---- fused sims + top2 + finalize (64 rows/block, pn-in-registers) ----
    sims64_kernel<<<B / 64, 256, 0, stream>>>(
        pnh, pnl, eTh, eTl, out, list, cnt, B);

    // ---- fast exact recheck of ambiguous rows ----
    recheck_row_kernel<<<2048, 256, 0, stream>>>(
        img, W1, b1, W2, b2, W3, b3, enT, list, cnt, out, B);
}